// Round 11
// baseline (1233.110 us; speedup 1.0000x reference)
//
#include <hip/hip_runtime.h>
#include <stdint.h>

typedef unsigned short u16;
typedef uint32_t u32;
typedef __bf16 bf16x8 __attribute__((ext_vector_type(8)));
typedef float f32x4 __attribute__((ext_vector_type(4)));

constexpr int T_ = 32768, D_ = 256, H_ = 8, L_ = 4, B_ = 64, NSENS_ = 5160;
constexpr int MGEO_ = 5248;  // NSENS_ padded to 41*128

template <bool Bv> struct bconst { static constexpr bool value = Bv; };

__device__ __forceinline__ u16 f2b(float f) {
  uint32_t u = __builtin_bit_cast(uint32_t, f);
  u += 0x7fffu + ((u >> 16) & 1u);
  return (u16)(u >> 16);
}
__device__ __forceinline__ float fexp2(float x) {
  float r;
  asm("v_exp_f32 %0, %1" : "=v"(r) : "v"(x));
  return r;
}
__device__ __forceinline__ u32 cvtpk(float lo, float hi) {
  u32 r;
  asm("v_cvt_pk_bf16_f32 %0, %1, %2" : "=v"(r) : "v"(lo), "v"(hi));
  return r;
}

__device__ __forceinline__ void gload16(const void* g, void* l) {
  __builtin_amdgcn_global_load_lds(
      (const __attribute__((address_space(1))) void*)g,
      (__attribute__((address_space(3))) void*)l, 16, 0, 0);
}

// ---------------- offsets via binary search (sorted dom_to_event_idx) --------
__global__ void k_offsets(const int* __restrict__ d2e, int* __restrict__ offs) {
  int t = threadIdx.x;
  if (t > B_) return;
  int lo = 0, hi = T_;
  while (lo < hi) { int mid = (lo + hi) >> 1; if (d2e[mid] < t) lo = mid + 1; else hi = mid; }
  offs[t] = lo;
}

// ---------------- f32 -> bf16 weight conversion ------------------------------
__global__ void k_f2b(const float* __restrict__ s, u16* __restrict__ d, int n) {
  int i = blockIdx.x * blockDim.x + threadIdx.x;
  int str = gridDim.x * blockDim.x;
  for (; i < n; i += str) d[i] = f2b(s[i]);
}

// ---------------- geo MLP stage 1: h1 = gelu(geom/500 @ w1^T + b1), bf16 -----
__global__ void k_geo1(const float* __restrict__ geom, const float* __restrict__ w1,
                       const float* __restrict__ b1, u16* __restrict__ h1) {
  int i = blockIdx.x * blockDim.x + threadIdx.x;
  if (i >= NSENS_ * 128) return;
  int s = i >> 7, c = i & 127;
  float g0 = geom[s * 3 + 0] * (1.0f / 500.0f);
  float g1 = geom[s * 3 + 1] * (1.0f / 500.0f);
  float g2 = geom[s * 3 + 2] * (1.0f / 500.0f);
  float a = g0 * w1[c * 3 + 0] + g1 * w1[c * 3 + 1] + g2 * w1[c * 3 + 2] + b1[c];
  float g = 0.5f * a * (1.0f + erff(a * 0.70710678118654752f));
  h1[i] = f2b(g);
}

// ---------------- feat + layer-0 LN1: x = de + ge[dom]; h = LN(x) ------------
__global__ void k_featln(const float4* __restrict__ de, const float4* __restrict__ ge,
                         const int* __restrict__ dom_ids, const float* __restrict__ w,
                         const float* __restrict__ b, float4* __restrict__ x,
                         u16* __restrict__ h) {
  int row = blockIdx.x * 4 + (threadIdx.x >> 6);
  int lane = threadIdx.x & 63;
  int sid = dom_ids[row];
  float4 a = de[row * 64 + lane];
  float4 g = ge[sid * 64 + lane];
  float4 v;
  v.x = a.x + g.x; v.y = a.y + g.y; v.z = a.z + g.z; v.w = a.w + g.w;
  x[row * 64 + lane] = v;
  float s = v.x + v.y + v.z + v.w;
  float q = v.x * v.x + v.y * v.y + v.z * v.z + v.w * v.w;
#pragma unroll
  for (int m = 1; m < 64; m <<= 1) { s += __shfl_xor(s, m); q += __shfl_xor(q, m); }
  float mean = s * (1.0f / 256.0f);
  float var = fmaxf(q * (1.0f / 256.0f) - mean * mean, 0.0f);
  float rs = 1.0f / sqrtf(var + 1e-5f);
  float4 wv = *(const float4*)(w + lane * 4);
  float4 bv = *(const float4*)(b + lane * 4);
  ushort4 o;
  o.x = f2b((v.x - mean) * rs * wv.x + bv.x);
  o.y = f2b((v.y - mean) * rs * wv.y + bv.y);
  o.z = f2b((v.z - mean) * rs * wv.z + bv.z);
  o.w = f2b((v.w - mean) * rs * wv.w + bv.w);
  *(ushort4*)(h + (size_t)row * 256 + lane * 4) = o;
}

// ---------------- bf16 MFMA GEMM v2 (128x128 tile) ---------------------------
// EPI: 0 = bf16 out, 1 = relu->bf16, 2 = f32 residual accumulate, 3 = f32 store
template <int EPI>
__global__ __launch_bounds__(256) void k_gemm(const u16* __restrict__ A, const u16* __restrict__ W,
                                              const float* __restrict__ bias, void* __restrict__ out,
                                              int M, int N, int K, int NXB) {
  __shared__ __align__(16) u16 lds[4 * 8192];
  const int nb = gridDim.x;
  const int id = blockIdx.x;
  const int gid = ((nb & 7) == 0) ? ((id & 7) * (nb >> 3) + (id >> 3)) : id;
  const int by = gid / NXB, bx = gid % NXB;
  const int m0 = by * 128, n0 = bx * 128;
  const int tid = threadIdx.x, lane = tid & 63, wv = tid >> 6;
  const int wr = wv >> 1, wc = wv & 1;
  const int l16 = lane & 15, lhi = lane >> 4;
  f32x4 acc[4][4] = {};
  const int NK = K >> 6;

  auto stage = [&](int buf, int kt) {
    char* lbase = (char*)lds + buf * 32768;
#pragma unroll
    for (int c = 0; c < 4; ++c) {
      int pb = c * 4096 + wv * 1024;
      int p = pb + lane * 16;
      int o = p ^ (((p >> 9) & 1) << 5);
      int row = o >> 7, colb = o & 127;
      gload16((const char*)A + ((size_t)(m0 + row) * K) * 2 + kt * 128 + colb, lbase + pb);
      gload16((const char*)W + ((size_t)(n0 + row) * K) * 2 + kt * 128 + colb,
              lbase + 16384 + pb);
    }
  };
  auto compute = [&](int buf) {
    const char* la = (const char*)lds + buf * 32768;
    const char* lb = la + 16384;
#pragma unroll
    for (int ks = 0; ks < 2; ++ks) {
      bf16x8 af[4], bfr[4];
#pragma unroll
      for (int i = 0; i < 4; ++i) {
        int ra = wr * 64 + i * 16 + l16;
        int oa = ra * 128 + ks * 64 + lhi * 16;
        af[i] = *(const bf16x8*)(la + (oa ^ (((oa >> 9) & 1) << 5)));
        int rb = wc * 64 + i * 16 + l16;
        int ob2 = rb * 128 + ks * 64 + lhi * 16;
        bfr[i] = *(const bf16x8*)(lb + (ob2 ^ (((ob2 >> 9) & 1) << 5)));
      }
#pragma unroll
      for (int i = 0; i < 4; ++i)
#pragma unroll
        for (int j = 0; j < 4; ++j)
          acc[i][j] = __builtin_amdgcn_mfma_f32_16x16x32_bf16(af[i], bfr[j], acc[i][j], 0, 0, 0);
    }
  };

  stage(0, 0);
  for (int kt = 0; kt < NK; ++kt) {
    int cur = kt & 1;
    if (kt + 1 < NK) {
      stage(cur ^ 1, kt + 1);
      asm volatile("s_waitcnt vmcnt(8)" ::: "memory");
    } else {
      asm volatile("s_waitcnt vmcnt(0)" ::: "memory");
    }
    __builtin_amdgcn_s_barrier();
    __builtin_amdgcn_sched_barrier(0);
    compute(cur);
    __builtin_amdgcn_sched_barrier(0);
    __builtin_amdgcn_s_barrier();
  }

  float bv[4];
#pragma unroll
  for (int j = 0; j < 4; ++j) bv[j] = bias[n0 + wc * 64 + j * 16 + l16];

  if (EPI <= 1) {
    char* ob_ = (char*)lds;
#pragma unroll
    for (int i = 0; i < 4; ++i)
#pragma unroll
      for (int j = 0; j < 4; ++j)
#pragma unroll
        for (int r = 0; r < 4; ++r) {
          int row = wr * 64 + i * 16 + lhi * 4 + r;
          int col = wc * 64 + j * 16 + l16;
          float v = acc[i][j][r] + bv[j];
          if (EPI == 1) v = fmaxf(v, 0.0f);
          int byte = row * 256 + col * 2;
          *(u16*)(ob_ + (byte ^ ((row & 3) << 5))) = f2b(v);
        }
    __syncthreads();
    int row2 = tid >> 1, half = tid & 1;
    char* dst = (char*)out + ((size_t)(m0 + row2) * N + n0) * 2 + half * 128;
#pragma unroll
    for (int c2 = 0; c2 < 8; ++c2) {
      int byte = row2 * 256 + half * 128 + c2 * 16;
      uint4 t = *(const uint4*)(ob_ + (byte ^ ((row2 & 3) << 5)));
      *(uint4*)(dst + c2 * 16) = t;
    }
  } else {
#pragma unroll
    for (int i = 0; i < 4; ++i)
#pragma unroll
      for (int j = 0; j < 4; ++j)
#pragma unroll
        for (int r = 0; r < 4; ++r) {
          int m = m0 + wr * 64 + i * 16 + lhi * 4 + r;
          int n = n0 + wc * 64 + j * 16 + l16;
          float val = acc[i][j][r] + bv[j];
          if (EPI == 2)
            ((float*)out)[(size_t)m * N + n] += val;
          else
            ((float*)out)[(size_t)m * N + n] = val;
        }
  }
}

// ---------------- fused GEMM + residual + LayerNorm --------------------------
__global__ __launch_bounds__(256) void k_gemm_ln(const u16* __restrict__ A,
                                                 const u16* __restrict__ W,
                                                 const float* __restrict__ bias,
                                                 const float* __restrict__ lnw,
                                                 const float* __restrict__ lnb,
                                                 float* __restrict__ x,
                                                 u16* __restrict__ hout, int K) {
  __shared__ __align__(16) u16 lds[2 * 20480];
  const int nb = gridDim.x;
  const int id = blockIdx.x;
  const int gid = (id & 7) * (nb >> 3) + (id >> 3);
  const int m0 = gid * 64;
  const int tid = threadIdx.x, lane = tid & 63, wv = tid >> 6;
  const int l16 = lane & 15, lhi = lane >> 4;
  f32x4 acc[4][4] = {};
  const int NK = K >> 6;

  auto stage = [&](int buf, int kt) {
    char* lbase = (char*)lds + buf * 40960;
#pragma unroll
    for (int c = 0; c < 10; ++c) {
      int pb = c * 4096 + wv * 1024;
      int p, reg;
      if (pb < 8192) { p = pb; reg = 0; } else { p = pb - 8192; reg = 1; }
      int pl = p + lane * 16;
      int o = pl ^ (((pl >> 9) & 1) << 5);
      int row = o >> 7, colb = o & 127;
      const char* src = reg == 0
          ? (const char*)A + ((size_t)(m0 + row) * K) * 2 + kt * 128 + colb
          : (const char*)W + ((size_t)row * K) * 2 + kt * 128 + colb;
      gload16(src, lbase + (reg ? 8192 : 0) + p);
    }
  };
  auto compute = [&](int buf) {
    const char* la = (const char*)lds + buf * 40960;
    const char* lb = la + 8192;
#pragma unroll
    for (int ks = 0; ks < 2; ++ks) {
      bf16x8 af[4], bfr[4];
#pragma unroll
      for (int i = 0; i < 4; ++i) {
        int oa = (i * 16 + l16) * 128 + ks * 64 + lhi * 16;
        af[i] = *(const bf16x8*)(la + (oa ^ (((oa >> 9) & 1) << 5)));
        int ob2 = (wv * 64 + i * 16 + l16) * 128 + ks * 64 + lhi * 16;
        bfr[i] = *(const bf16x8*)(lb + (ob2 ^ (((ob2 >> 9) & 1) << 5)));
      }
#pragma unroll
      for (int i = 0; i < 4; ++i)
#pragma unroll
        for (int j = 0; j < 4; ++j)
          acc[i][j] = __builtin_amdgcn_mfma_f32_16x16x32_bf16(af[i], bfr[j], acc[i][j], 0, 0, 0);
    }
  };

  stage(0, 0);
  for (int kt = 0; kt < NK; ++kt) {
    int cur = kt & 1;
    if (kt + 1 < NK) {
      stage(cur ^ 1, kt + 1);
      asm volatile("s_waitcnt vmcnt(10)" ::: "memory");
    } else {
      asm volatile("s_waitcnt vmcnt(0)" ::: "memory");
    }
    __builtin_amdgcn_s_barrier();
    __builtin_amdgcn_sched_barrier(0);
    compute(cur);
    __builtin_amdgcn_sched_barrier(0);
    __builtin_amdgcn_s_barrier();
  }

  float bv[4], wl[4], bl[4];
#pragma unroll
  for (int j = 0; j < 4; ++j) {
    int col = wv * 64 + j * 16 + l16;
    bv[j] = bias[col];
    wl[j] = lnw[col];
    bl[j] = lnb[col];
  }
#pragma unroll
  for (int i = 0; i < 4; ++i)
#pragma unroll
    for (int r = 0; r < 4; ++r) {
      int row = i * 16 + lhi * 4 + r;
#pragma unroll
      for (int j = 0; j < 4; ++j) {
        int col = wv * 64 + j * 16 + l16;
        acc[i][j][r] += bv[j] + x[(size_t)(m0 + row) * 256 + col];
      }
    }
  float* lr = (float*)lds;
  __syncthreads();
#pragma unroll
  for (int i = 0; i < 4; ++i)
#pragma unroll
    for (int r = 0; r < 4; ++r) {
      float s = 0.0f, q = 0.0f;
#pragma unroll
      for (int j = 0; j < 4; ++j) { float v = acc[i][j][r]; s += v; q += v * v; }
#pragma unroll
      for (int m = 1; m < 16; m <<= 1) { s += __shfl_xor(s, m); q += __shfl_xor(q, m); }
      if (l16 == 0) {
        int row = i * 16 + lhi * 4 + r;
        lr[wv * 64 + row] = s;
        lr[256 + wv * 64 + row] = q;
      }
    }
  __syncthreads();
  if (tid < 64) {
    float s = lr[tid] + lr[64 + tid] + lr[128 + tid] + lr[192 + tid];
    float q = lr[256 + tid] + lr[320 + tid] + lr[384 + tid] + lr[448 + tid];
    float mean = s * (1.0f / 256.0f);
    float var = fmaxf(q * (1.0f / 256.0f) - mean * mean, 0.0f);
    lr[512 + tid * 2] = mean;
    lr[512 + tid * 2 + 1] = 1.0f / sqrtf(var + 1e-5f);
  }
  __syncthreads();
#pragma unroll
  for (int i = 0; i < 4; ++i)
#pragma unroll
    for (int r = 0; r < 4; ++r) {
      int row = i * 16 + lhi * 4 + r;
      float mean = lr[512 + row * 2];
      float rstd = lr[512 + row * 2 + 1];
#pragma unroll
      for (int j = 0; j < 4; ++j) {
        int col = wv * 64 + j * 16 + l16;
        float v = acc[i][j][r];
        x[(size_t)(m0 + row) * 256 + col] = v;
        hout[(size_t)(m0 + row) * 256 + col] = f2b((v - mean) * rstd * wl[j] + bl[j]);
      }
    }
}

// ---------------- flash attention v8: r7 config + K ping-pong prefetch -------
// Block = (event, 32-q-chunk); 8 waves = 8 heads. K for tile t+1 issued before
// compute of tile t (hides L2 latency under QK/softmax/PV). V gathers issued
// at compute start, consumed after softmax.
__global__ __launch_bounds__(512, 4) void k_attn(const u16* __restrict__ qkv,
                                                 const int* __restrict__ offs,
                                                 u16* __restrict__ ao) {
  const int e = blockIdx.x, qc = blockIdx.y;
  const int off = offs[e], Se = offs[e + 1] - off;
  if (qc * 32 >= Se) return;
  const int tid = threadIdx.x, lane = tid & 63, h = tid >> 6;
  const int l16 = lane & 15, lhi = lane >> 4;

  __shared__ __align__(16) char smem[8 * 4608];
  char* pw = smem + h * 4608;

  bf16x8 qf[2];
#pragma unroll
  for (int qt = 0; qt < 2; ++qt) {
    int qrow = qc * 32 + qt * 16 + l16;
    int g = off + min(qrow, Se - 1);
    qf[qt] = *(const bf16x8*)(qkv + (size_t)g * 768 + h * 32 + lhi * 8);
  }

  f32x4 ob[2][2] = {};
  float m_[2], l_[2];
#pragma unroll
  for (int qt = 0; qt < 2; ++qt) { m_[qt] = -1e30f; l_[qt] = 0.0f; }
  const float SCL2 = 0.25506974760143f;  // (1/sqrt(32)) * log2(e)

  auto loadK = [&](int kb, bf16x8 (&kf)[4]) {
#pragma unroll
    for (int kt = 0; kt < 4; ++kt) {
      int key = min(kb + kt * 16 + l16, Se - 1);
      kf[kt] = *(const bf16x8*)(qkv + (size_t)(off + key) * 768 + 256 + h * 32 + lhi * 8);
    }
  };

  auto compute = [&](int kb, bf16x8 (&kf)[4], auto mc) {
    constexpr bool MASK = decltype(mc)::value;
    // V gathers issued now, consumed after softmax (~400cy later)
    u16 va0[2][8], va1[2][8];
#pragma unroll
    for (int k2 = 0; k2 < 2; ++k2)
#pragma unroll
      for (int j = 0; j < 8; ++j) {
        int key = min(kb + k2 * 32 + lhi * 8 + j, Se - 1);
        const u16* p = qkv + (size_t)(off + key) * 768 + 512 + h * 32 + l16;
        va0[k2][j] = p[0];
        va1[k2][j] = p[16];
      }

#pragma unroll
    for (int qt = 0; qt < 2; ++qt) {
      char* pq = pw + qt * 2304;
      f32x4 sc[4];
      __builtin_amdgcn_s_setprio(1);
#pragma unroll
      for (int kt = 0; kt < 4; ++kt) {
        f32x4 z = {};
        sc[kt] = __builtin_amdgcn_mfma_f32_16x16x32_bf16(kf[kt], qf[qt], z, 0, 0, 0);
      }
      __builtin_amdgcn_s_setprio(0);
      float pv[16], pm = -1e30f;
#pragma unroll
      for (int kt = 0; kt < 4; ++kt)
#pragma unroll
        for (int r = 0; r < 4; ++r) {
          float s = sc[kt][r] * SCL2;
          if (MASK) {
            if (kb + kt * 16 + lhi * 4 + r >= Se) s = -1e30f;
          }
          pv[kt * 4 + r] = s;
          pm = fmaxf(pm, s);
        }
      pm = fmaxf(pm, __shfl_xor(pm, 16));
      pm = fmaxf(pm, __shfl_xor(pm, 32));
      float mn = m_[qt];
      if (!__all(pm <= mn + 11.09f)) {
        mn = fmaxf(mn, pm);
        float csc = fexp2(m_[qt] - mn);
        m_[qt] = mn;
        l_[qt] *= csc;
#pragma unroll
        for (int dt = 0; dt < 2; ++dt)
#pragma unroll
          for (int r = 0; r < 4; ++r) ob[qt][dt][r] *= csc;
      }
      float rs = 0.0f;
#pragma unroll
      for (int i = 0; i < 16; ++i) {
        pv[i] = fexp2(pv[i] - mn);
        rs += pv[i];
      }
      rs += __shfl_xor(rs, 16);
      rs += __shfl_xor(rs, 32);
      l_[qt] += rs;
#pragma unroll
      for (int kt = 0; kt < 4; ++kt)
#pragma unroll
        for (int c = 0; c < 2; ++c)
          *(u32*)(pq + l16 * 144 + (kt * 16 + lhi * 4 + 2 * c) * 2) =
              cvtpk(pv[kt * 4 + 2 * c], pv[kt * 4 + 2 * c + 1]);
      // assemble V^T frags (first use of the early V gathers)
      bf16x8 vf[2][2];
#pragma unroll
      for (int k2 = 0; k2 < 2; ++k2) {
        union { u16 a[8]; bf16x8 v; } u0, u1;
#pragma unroll
        for (int j = 0; j < 8; ++j) { u0.a[j] = va0[k2][j]; u1.a[j] = va1[k2][j]; }
        vf[0][k2] = u0.v;
        vf[1][k2] = u1.v;
      }
      __builtin_amdgcn_s_setprio(1);
#pragma unroll
      for (int k2 = 0; k2 < 2; ++k2) {
        bf16x8 pf = *(const bf16x8*)(pq + l16 * 144 + k2 * 64 + lhi * 16);
#pragma unroll
        for (int dt = 0; dt < 2; ++dt)
          ob[qt][dt] = __builtin_amdgcn_mfma_f32_16x16x32_bf16(vf[dt][k2], pf, ob[qt][dt], 0, 0, 0);
      }
      __builtin_amdgcn_s_setprio(0);
    }
  };

  const int nt = (Se + 63) >> 6;
  const bool tail = (Se & 63) != 0;
  bf16x8 kfA[4], kfB[4];
  loadK(0, kfA);
  int t = 0;
  for (;;) {
    if (t + 1 < nt) loadK((t + 1) << 6, kfB);
    if (t == nt - 1) {
      if (tail) compute(t << 6, kfA, bconst<true>{});
      else      compute(t << 6, kfA, bconst<false>{});
      break;
    }
    compute(t << 6, kfA, bconst<false>{});
    ++t;
    if (t + 1 < nt) loadK((t + 1) << 6, kfA);
    if (t == nt - 1) {
      if (tail) compute(t << 6, kfB, bconst<true>{});
      else      compute(t << 6, kfB, bconst<false>{});
      break;
    }
    compute(t << 6, kfB, bconst<false>{});
    ++t;
  }

#pragma unroll
  for (int qt = 0; qt < 2; ++qt) {
    float inv = 1.0f / l_[qt];
#pragma unroll
    for (int dt = 0; dt < 2; ++dt)
#pragma unroll
      for (int c = 0; c < 2; ++c)
        *(u32*)(pw + (qt * 16 + l16) * 80 + (dt * 16 + lhi * 4 + 2 * c) * 2) =
            cvtpk(ob[qt][dt][2 * c] * inv, ob[qt][dt][2 * c + 1] * inv);
  }
  asm volatile("s_waitcnt lgkmcnt(0)" ::: "memory");
  __builtin_amdgcn_sched_barrier(0);
  int qrow = qc * 32 + lane;
  if (lane < 32 && qrow < Se) {
#pragma unroll
    for (int c = 0; c < 4; ++c) {
      uint4 t4 = *(const uint4*)(pw + lane * 80 + c * 16);
      *(uint4*)((char*)ao + (size_t)(off + qrow) * 512 + h * 64 + c * 16) = t4;
    }
  }
}

// ---------------- masked mean pooling: split-K partials ----------------------
__global__ void k_pool(const float* __restrict__ x, const int* __restrict__ offs,
                       float* __restrict__ pws) {
  int e = blockIdx.x, s = blockIdx.y, t = threadIdx.x;
  int off = offs[e], cnt = offs[e + 1] - off;
  int r0 = (cnt * s) >> 4, r1 = (cnt * (s + 1)) >> 4;
  float acc = 0.0f;
  for (int r = r0; r < r1; ++r) acc += x[(size_t)(off + r) * 256 + t];
  pws[((e << 4) + s) * 256 + t] = acc;
}

// ---------------- prediction head + L2 normalize -----------------------------
__global__ void k_head(const float* __restrict__ pws, const int* __restrict__ offs,
                       const float* __restrict__ w1, const float* __restrict__ b1,
                       const float* __restrict__ w2, const float* __restrict__ b2,
                       float* __restrict__ out) {
  __shared__ float le[256], hb[256], vec[3];
  int e = blockIdx.x, t = threadIdx.x;
  int cnt = offs[e + 1] - offs[e];
  float acc0 = 0.0f;
#pragma unroll
  for (int s = 0; s < 16; ++s) acc0 += pws[((e << 4) + s) * 256 + t];
  le[t] = acc0 / (float)max(cnt, 1);
  __syncthreads();
  float acc = b1[t];
  const float* wr = w1 + t * 256;
#pragma unroll 8
  for (int k = 0; k < 256; ++k) acc += le[k] * wr[k];
  hb[t] = fmaxf(acc, 0.0f);
  __syncthreads();
  if (t < 3) {
    float a = b2[t];
    const float* w = w2 + t * 256;
    for (int k = 0; k < 256; ++k) a += hb[k] * w[k];
    vec[t] = a;
  }
  __syncthreads();
  if (t < 3) {
    float n = sqrtf(vec[0] * vec[0] + vec[1] * vec[1] + vec[2] * vec[2]);
    out[e * 3 + t] = vec[t] / (n + 1e-8f);
  }
}

// ---------------- launch ------------------------------------------------------
extern "C" void kernel_launch(void* const* d_in, const int* in_sizes, int n_in,
                              void* d_out, int out_size, void* d_ws, size_t ws_size,
                              hipStream_t stream) {
  const float* dom_emb = (const float*)d_in[0];
  const float* geometry = (const float*)d_in[1];
  const float* geo_w1 = (const float*)d_in[2];
  const float* geo_b1 = (const float*)d_in[3];
  const float* geo_w2 = (const float*)d_in[4];
  const float* geo_b2 = (const float*)d_in[5];
  const float* qkv_w = (const float*)d_in[6];
  const float* qkv_b = (const float*)d_in[7];
  const float* out_w = (const float*)d_in[8];
  const float* out_b = (const float*)d_in[9];
  const float* ln1_w = (const float*)d_in[10];
  const float* ln1_b = (const float*)d_in[11];
  const float* ln2_w = (const float*)d_in[12];
  const float* ln2_b = (const float*)d_in[13];
  const float* ffn_w1 = (const float*)d_in[14];
  const float* ffn_b1 = (const float*)d_in[15];
  const float* ffn_w2 = (const float*)d_in[16];
  const float* ffn_b2 = (const float*)d_in[17];
  const float* head_w1 = (const float*)d_in[18];
  const float* head_b1 = (const float*)d_in[19];
  const float* head_w2 = (const float*)d_in[20];
  const float* head_b2 = (const float*)d_in[21];
  const int* dom_ids = (const int*)d_in[22];
  const int* d2e = (const int*)d_in[23];

  char* ws = (char*)d_ws;
  constexpr size_t OFF_OFFS = 0;
  constexpr size_t OFF_WBF = 512;
  constexpr size_t OFF_W2B = OFF_WBF + 3145728ull * 2;
  constexpr size_t OFF_H1 = OFF_W2B + 32768ull * 2;
  constexpr size_t OFF_GE = OFF_H1 + (size_t)MGEO_ * 128 * 2;
  constexpr size_t OFF_X = (OFF_GE + (size_t)MGEO_ * 256 * 4 + 255) & ~255ull;
  constexpr size_t OFF_H = OFF_X + (size_t)T_ * 256 * 4;
  constexpr size_t OFF_BIG = OFF_H + (size_t)T_ * 256 * 2;
  constexpr size_t OFF_PWS = OFF_BIG + (size_t)T_ * 1024 * 2;

  int* offs = (int*)(ws + OFF_OFFS);
  u16* wbf = (u16*)(ws + OFF_WBF);
  u16* wbf_qkv = wbf;
  u16* wbf_out = wbf + 786432;
  u16* wbf_f1 = wbf + 1048576;
  u16* wbf_f2 = wbf + 2097152;
  u16* w2b = (u16*)(ws + OFF_W2B);
  u16* h1 = (u16*)(ws + OFF_H1);
  float* ge = (float*)(ws + OFF_GE);
  float* x = (float*)(ws + OFF_X);
  u16* h = (u16*)(ws + OFF_H);
  u16* big = (u16*)(ws + OFF_BIG);
  float* pws = (float*)(ws + OFF_PWS);

  k_offsets<<<1, 128, 0, stream>>>(d2e, offs);
  k_f2b<<<256, 256, 0, stream>>>(qkv_w, wbf_qkv, L_ * 768 * 256);
  k_f2b<<<128, 256, 0, stream>>>(out_w, wbf_out, L_ * 256 * 256);
  k_f2b<<<256, 256, 0, stream>>>(ffn_w1, wbf_f1, L_ * 1024 * 256);
  k_f2b<<<256, 256, 0, stream>>>(ffn_w2, wbf_f2, L_ * 256 * 1024);
  k_f2b<<<32, 256, 0, stream>>>(geo_w2, w2b, 256 * 128);
  k_geo1<<<(NSENS_ * 128 + 255) / 256, 256, 0, stream>>>(geometry, geo_w1, geo_b1, h1);
  k_gemm<3><<<(MGEO_ / 128) * 2, 256, 0, stream>>>(h1, w2b, geo_b2, ge,
                                                   MGEO_, 256, 128, 2);
  k_featln<<<T_ / 4, 256, 0, stream>>>((const float4*)dom_emb, (const float4*)ge,
                                       dom_ids, ln1_w, ln1_b, (float4*)x, h);
  for (int l = 0; l < L_; ++l) {
    k_gemm<0><<<6 * 256, 256, 0, stream>>>(h, wbf_qkv + l * 196608, qkv_b + l * 768,
                                           big, T_, 768, 256, 6);
    k_attn<<<dim3(B_, 24), 512, 0, stream>>>(big, offs, h);
    k_gemm_ln<<<T_ / 64, 256, 0, stream>>>(h, wbf_out + l * 65536, out_b + l * 256,
                                           ln2_w + l * 256, ln2_b + l * 256, x, h, 256);
    k_gemm<1><<<8 * 256, 256, 0, stream>>>(h, wbf_f1 + l * 262144, ffn_b1 + l * 1024,
                                           big, T_, 1024, 256, 8);
    if (l < L_ - 1) {
      k_gemm_ln<<<T_ / 64, 256, 0, stream>>>(big, wbf_f2 + l * 262144, ffn_b2 + l * 256,
                                             ln1_w + (l + 1) * 256, ln1_b + (l + 1) * 256,
                                             x, h, 1024);
    } else {
      k_gemm<2><<<2 * 256, 256, 0, stream>>>(big, wbf_f2 + l * 262144, ffn_b2 + l * 256,
                                             x, T_, 256, 1024, 2);
    }
  }
  k_pool<<<dim3(B_, 16), 256, 0, stream>>>(x, offs, pws);
  k_head<<<B_, 256, 0, stream>>>(pws, offs, head_w1, head_b1, head_w2, head_b2, (float*)d_out);
}

// Round 12
// 1023.636 us; speedup vs baseline: 1.2046x; 1.2046x over previous
//
#include <hip/hip_runtime.h>
#include <stdint.h>

typedef unsigned short u16;
typedef uint32_t u32;
typedef __bf16 bf16x8 __attribute__((ext_vector_type(8)));
typedef float f32x4 __attribute__((ext_vector_type(4)));

constexpr int T_ = 32768, D_ = 256, H_ = 8, L_ = 4, B_ = 64, NSENS_ = 5160;
constexpr int MGEO_ = 5248;  // NSENS_ padded to 41*128

template <bool Bv> struct bconst { static constexpr bool value = Bv; };

__device__ __forceinline__ u16 f2b(float f) {
  uint32_t u = __builtin_bit_cast(uint32_t, f);
  u += 0x7fffu + ((u >> 16) & 1u);
  return (u16)(u >> 16);
}
__device__ __forceinline__ float fexp2(float x) {
  float r;
  asm("v_exp_f32 %0, %1" : "=v"(r) : "v"(x));
  return r;
}
__device__ __forceinline__ u32 cvtpk(float lo, float hi) {
  u32 r;
  asm("v_cvt_pk_bf16_f32 %0, %1, %2" : "=v"(r) : "v"(lo), "v"(hi));
  return r;
}

__device__ __forceinline__ void gload16(const void* g, void* l) {
  __builtin_amdgcn_global_load_lds(
      (const __attribute__((address_space(1))) void*)g,
      (__attribute__((address_space(3))) void*)l, 16, 0, 0);
}

// ---------------- offsets via binary search (sorted dom_to_event_idx) --------
__global__ void k_offsets(const int* __restrict__ d2e, int* __restrict__ offs) {
  int t = threadIdx.x;
  if (t > B_) return;
  int lo = 0, hi = T_;
  while (lo < hi) { int mid = (lo + hi) >> 1; if (d2e[mid] < t) lo = mid + 1; else hi = mid; }
  offs[t] = lo;
}

// ---------------- f32 -> bf16 weight conversion ------------------------------
__global__ void k_f2b(const float* __restrict__ s, u16* __restrict__ d, int n) {
  int i = blockIdx.x * blockDim.x + threadIdx.x;
  int str = gridDim.x * blockDim.x;
  for (; i < n; i += str) d[i] = f2b(s[i]);
}

// ---------------- geo MLP stage 1: h1 = gelu(geom/500 @ w1^T + b1), bf16 -----
__global__ void k_geo1(const float* __restrict__ geom, const float* __restrict__ w1,
                       const float* __restrict__ b1, u16* __restrict__ h1) {
  int i = blockIdx.x * blockDim.x + threadIdx.x;
  if (i >= NSENS_ * 128) return;
  int s = i >> 7, c = i & 127;
  float g0 = geom[s * 3 + 0] * (1.0f / 500.0f);
  float g1 = geom[s * 3 + 1] * (1.0f / 500.0f);
  float g2 = geom[s * 3 + 2] * (1.0f / 500.0f);
  float a = g0 * w1[c * 3 + 0] + g1 * w1[c * 3 + 1] + g2 * w1[c * 3 + 2] + b1[c];
  float g = 0.5f * a * (1.0f + erff(a * 0.70710678118654752f));
  h1[i] = f2b(g);
}

// ---------------- feat + layer-0 LN1: x = de + ge[dom]; h = LN(x) ------------
__global__ void k_featln(const float4* __restrict__ de, const float4* __restrict__ ge,
                         const int* __restrict__ dom_ids, const float* __restrict__ w,
                         const float* __restrict__ b, float4* __restrict__ x,
                         u16* __restrict__ h) {
  int row = blockIdx.x * 4 + (threadIdx.x >> 6);
  int lane = threadIdx.x & 63;
  int sid = dom_ids[row];
  float4 a = de[row * 64 + lane];
  float4 g = ge[sid * 64 + lane];
  float4 v;
  v.x = a.x + g.x; v.y = a.y + g.y; v.z = a.z + g.z; v.w = a.w + g.w;
  x[row * 64 + lane] = v;
  float s = v.x + v.y + v.z + v.w;
  float q = v.x * v.x + v.y * v.y + v.z * v.z + v.w * v.w;
#pragma unroll
  for (int m = 1; m < 64; m <<= 1) { s += __shfl_xor(s, m); q += __shfl_xor(q, m); }
  float mean = s * (1.0f / 256.0f);
  float var = fmaxf(q * (1.0f / 256.0f) - mean * mean, 0.0f);
  float rs = 1.0f / sqrtf(var + 1e-5f);
  float4 wv = *(const float4*)(w + lane * 4);
  float4 bv = *(const float4*)(b + lane * 4);
  ushort4 o;
  o.x = f2b((v.x - mean) * rs * wv.x + bv.x);
  o.y = f2b((v.y - mean) * rs * wv.y + bv.y);
  o.z = f2b((v.z - mean) * rs * wv.z + bv.z);
  o.w = f2b((v.w - mean) * rs * wv.w + bv.w);
  *(ushort4*)(h + (size_t)row * 256 + lane * 4) = o;
}

// ---------------- bf16 MFMA GEMM v3: single-buffer 32KB LDS ------------------
// EPI: 0 = bf16 out, 1 = relu->bf16, 2 = f32 residual accumulate, 3 = f32 store
template <int EPI>
__global__ __launch_bounds__(256) void k_gemm(const u16* __restrict__ A, const u16* __restrict__ W,
                                              const float* __restrict__ bias, void* __restrict__ out,
                                              int M, int N, int K, int NXB) {
  __shared__ __align__(16) u16 lds[2 * 8192];  // As 16KB + Ws 16KB
  const int nb = gridDim.x;
  const int id = blockIdx.x;
  const int gid = ((nb & 7) == 0) ? ((id & 7) * (nb >> 3) + (id >> 3)) : id;
  const int by = gid / NXB, bx = gid % NXB;
  const int m0 = by * 128, n0 = bx * 128;
  const int tid = threadIdx.x, lane = tid & 63, wv = tid >> 6;
  const int wr = wv >> 1, wc = wv & 1;
  const int l16 = lane & 15, lhi = lane >> 4;
  f32x4 acc[4][4] = {};
  const int NK = K >> 6;

  for (int kt = 0; kt < NK; ++kt) {
    __syncthreads();  // WAR: all waves done reading previous tile
#pragma unroll
    for (int c = 0; c < 4; ++c) {
      int pb = c * 4096 + wv * 1024;
      int p = pb + lane * 16;
      int o = p ^ (((p >> 9) & 1) << 5);
      int row = o >> 7, colb = o & 127;
      gload16((const char*)A + ((size_t)(m0 + row) * K) * 2 + kt * 128 + colb,
              (char*)lds + pb);
      gload16((const char*)W + ((size_t)(n0 + row) * K) * 2 + kt * 128 + colb,
              (char*)lds + 16384 + pb);
    }
    __syncthreads();  // RAW: drains vmcnt, LDS valid
    const char* la = (const char*)lds;
    const char* lb = la + 16384;
#pragma unroll
    for (int ks = 0; ks < 2; ++ks) {
      bf16x8 af[4], bfr[4];
#pragma unroll
      for (int i = 0; i < 4; ++i) {
        int ra = wr * 64 + i * 16 + l16;
        int oa = ra * 128 + ks * 64 + lhi * 16;
        af[i] = *(const bf16x8*)(la + (oa ^ (((oa >> 9) & 1) << 5)));
        int rb = wc * 64 + i * 16 + l16;
        int ob2 = rb * 128 + ks * 64 + lhi * 16;
        bfr[i] = *(const bf16x8*)(lb + (ob2 ^ (((ob2 >> 9) & 1) << 5)));
      }
#pragma unroll
      for (int i = 0; i < 4; ++i)
#pragma unroll
        for (int j = 0; j < 4; ++j)
          acc[i][j] = __builtin_amdgcn_mfma_f32_16x16x32_bf16(af[i], bfr[j], acc[i][j], 0, 0, 0);
    }
  }

  float bv[4];
#pragma unroll
  for (int j = 0; j < 4; ++j) bv[j] = bias[n0 + wc * 64 + j * 16 + l16];

  if (EPI <= 1) {
    __syncthreads();  // all waves done with compute reads before bounce reuse
    char* ob_ = (char*)lds;
#pragma unroll
    for (int i = 0; i < 4; ++i)
#pragma unroll
      for (int j = 0; j < 4; ++j)
#pragma unroll
        for (int r = 0; r < 4; ++r) {
          int row = wr * 64 + i * 16 + lhi * 4 + r;
          int col = wc * 64 + j * 16 + l16;
          float v = acc[i][j][r] + bv[j];
          if (EPI == 1) v = fmaxf(v, 0.0f);
          int byte = row * 256 + col * 2;
          *(u16*)(ob_ + (byte ^ ((row & 3) << 5))) = f2b(v);
        }
    __syncthreads();
    int row2 = tid >> 1, half = tid & 1;
    char* dst = (char*)out + ((size_t)(m0 + row2) * N + n0) * 2 + half * 128;
#pragma unroll
    for (int c2 = 0; c2 < 8; ++c2) {
      int byte = row2 * 256 + half * 128 + c2 * 16;
      uint4 t = *(const uint4*)(ob_ + (byte ^ ((row2 & 3) << 5)));
      *(uint4*)(dst + c2 * 16) = t;
    }
  } else {
#pragma unroll
    for (int i = 0; i < 4; ++i)
#pragma unroll
      for (int j = 0; j < 4; ++j)
#pragma unroll
        for (int r = 0; r < 4; ++r) {
          int m = m0 + wr * 64 + i * 16 + lhi * 4 + r;
          int n = n0 + wc * 64 + j * 16 + l16;
          float val = acc[i][j][r] + bv[j];
          if (EPI == 2)
            ((float*)out)[(size_t)m * N + n] += val;
          else
            ((float*)out)[(size_t)m * N + n] = val;
        }
  }
}

// ---------------- fused GEMM + residual + LayerNorm (single-buffer 40KB) -----
__global__ __launch_bounds__(256) void k_gemm_ln(const u16* __restrict__ A,
                                                 const u16* __restrict__ W,
                                                 const float* __restrict__ bias,
                                                 const float* __restrict__ lnw,
                                                 const float* __restrict__ lnb,
                                                 float* __restrict__ x,
                                                 u16* __restrict__ hout, int K) {
  __shared__ __align__(16) u16 lds[20480];  // As 8KB + Ws 32KB
  const int nb = gridDim.x;
  const int id = blockIdx.x;
  const int gid = (id & 7) * (nb >> 3) + (id >> 3);
  const int m0 = gid * 64;
  const int tid = threadIdx.x, lane = tid & 63, wv = tid >> 6;
  const int l16 = lane & 15, lhi = lane >> 4;
  f32x4 acc[4][4] = {};
  const int NK = K >> 6;

  for (int kt = 0; kt < NK; ++kt) {
    __syncthreads();
#pragma unroll
    for (int c = 0; c < 10; ++c) {
      int pb = c * 4096 + wv * 1024;
      int p, reg;
      if (pb < 8192) { p = pb; reg = 0; } else { p = pb - 8192; reg = 1; }
      int pl = p + lane * 16;
      int o = pl ^ (((pl >> 9) & 1) << 5);
      int row = o >> 7, colb = o & 127;
      const char* src = reg == 0
          ? (const char*)A + ((size_t)(m0 + row) * K) * 2 + kt * 128 + colb
          : (const char*)W + ((size_t)row * K) * 2 + kt * 128 + colb;
      gload16(src, (char*)lds + (reg ? 8192 : 0) + p);
    }
    __syncthreads();
    const char* la = (const char*)lds;
    const char* lb = la + 8192;
#pragma unroll
    for (int ks = 0; ks < 2; ++ks) {
      bf16x8 af[4], bfr[4];
#pragma unroll
      for (int i = 0; i < 4; ++i) {
        int oa = (i * 16 + l16) * 128 + ks * 64 + lhi * 16;
        af[i] = *(const bf16x8*)(la + (oa ^ (((oa >> 9) & 1) << 5)));
        int ob2 = (wv * 64 + i * 16 + l16) * 128 + ks * 64 + lhi * 16;
        bfr[i] = *(const bf16x8*)(lb + (ob2 ^ (((ob2 >> 9) & 1) << 5)));
      }
#pragma unroll
      for (int i = 0; i < 4; ++i)
#pragma unroll
        for (int j = 0; j < 4; ++j)
          acc[i][j] = __builtin_amdgcn_mfma_f32_16x16x32_bf16(af[i], bfr[j], acc[i][j], 0, 0, 0);
    }
  }

  float bv[4], wl[4], bl[4];
#pragma unroll
  for (int j = 0; j < 4; ++j) {
    int col = wv * 64 + j * 16 + l16;
    bv[j] = bias[col];
    wl[j] = lnw[col];
    bl[j] = lnb[col];
  }
#pragma unroll
  for (int i = 0; i < 4; ++i)
#pragma unroll
    for (int r = 0; r < 4; ++r) {
      int row = i * 16 + lhi * 4 + r;
#pragma unroll
      for (int j = 0; j < 4; ++j) {
        int col = wv * 64 + j * 16 + l16;
        acc[i][j][r] += bv[j] + x[(size_t)(m0 + row) * 256 + col];
      }
    }
  float* lr = (float*)lds;
  __syncthreads();
#pragma unroll
  for (int i = 0; i < 4; ++i)
#pragma unroll
    for (int r = 0; r < 4; ++r) {
      float s = 0.0f, q = 0.0f;
#pragma unroll
      for (int j = 0; j < 4; ++j) { float v = acc[i][j][r]; s += v; q += v * v; }
#pragma unroll
      for (int m = 1; m < 16; m <<= 1) { s += __shfl_xor(s, m); q += __shfl_xor(q, m); }
      if (l16 == 0) {
        int row = i * 16 + lhi * 4 + r;
        lr[wv * 64 + row] = s;
        lr[256 + wv * 64 + row] = q;
      }
    }
  __syncthreads();
  if (tid < 64) {
    float s = lr[tid] + lr[64 + tid] + lr[128 + tid] + lr[192 + tid];
    float q = lr[256 + tid] + lr[320 + tid] + lr[384 + tid] + lr[448 + tid];
    float mean = s * (1.0f / 256.0f);
    float var = fmaxf(q * (1.0f / 256.0f) - mean * mean, 0.0f);
    lr[512 + tid * 2] = mean;
    lr[512 + tid * 2 + 1] = 1.0f / sqrtf(var + 1e-5f);
  }
  __syncthreads();
#pragma unroll
  for (int i = 0; i < 4; ++i)
#pragma unroll
    for (int r = 0; r < 4; ++r) {
      int row = i * 16 + lhi * 4 + r;
      float mean = lr[512 + row * 2];
      float rstd = lr[512 + row * 2 + 1];
#pragma unroll
      for (int j = 0; j < 4; ++j) {
        int col = wv * 64 + j * 16 + l16;
        float v = acc[i][j][r];
        x[(size_t)(m0 + row) * 256 + col] = v;
        hout[(size_t)(m0 + row) * 256 + col] = f2b((v - mean) * rstd * wl[j] + bl[j]);
      }
    }
}

// ---------------- flash attention (r10 proven version, 82us) ------------------
// Block = (event, 32-q-chunk); 8 waves = 8 heads, independent (no barriers).
__global__ __launch_bounds__(512, 4) void k_attn(const u16* __restrict__ qkv,
                                                 const int* __restrict__ offs,
                                                 u16* __restrict__ ao) {
  const int e = blockIdx.x, qc = blockIdx.y;
  const int off = offs[e], Se = offs[e + 1] - off;
  if (qc * 32 >= Se) return;
  const int tid = threadIdx.x, lane = tid & 63, h = tid >> 6;
  const int l16 = lane & 15, lhi = lane >> 4;

  __shared__ __align__(16) char smem[8 * 5120];
  char* pw = smem + h * 5120;

  bf16x8 qf[2];
#pragma unroll
  for (int qt = 0; qt < 2; ++qt) {
    int qrow = qc * 32 + qt * 16 + l16;
    int g = off + min(qrow, Se - 1);
    qf[qt] = *(const bf16x8*)(qkv + (size_t)g * 768 + h * 32 + lhi * 8);
  }

  f32x4 ob[2][2] = {};
  float m_[2], l_[2];
#pragma unroll
  for (int qt = 0; qt < 2; ++qt) { m_[qt] = -1e30f; l_[qt] = 0.0f; }
  const float SCL2 = 0.25506974760143f;  // (1/sqrt(32)) * log2(e)

  auto do_tile = [&](int kb, auto mc) {
    constexpr bool MASK = decltype(mc)::value;
    bf16x8 kf[4];
#pragma unroll
    for (int kt = 0; kt < 4; ++kt) {
      int key = kb + kt * 16 + l16;
      if (MASK) key = min(key, Se - 1);
      kf[kt] = *(const bf16x8*)(qkv + (size_t)(off + key) * 768 + 256 + h * 32 + lhi * 8);
    }
    u16 va0[2][8], va1[2][8];
#pragma unroll
    for (int k2 = 0; k2 < 2; ++k2)
#pragma unroll
      for (int j = 0; j < 8; ++j) {
        int key = kb + k2 * 32 + lhi * 8 + j;
        if (MASK) key = min(key, Se - 1);
        const u16* p = qkv + (size_t)(off + key) * 768 + 512 + h * 32 + l16;
        va0[k2][j] = p[0];
        va1[k2][j] = p[16];
      }
    bf16x8 vf[2][2];
#pragma unroll
    for (int k2 = 0; k2 < 2; ++k2) {
      union { u16 a[8]; bf16x8 v; } u0, u1;
#pragma unroll
      for (int j = 0; j < 8; ++j) { u0.a[j] = va0[k2][j]; u1.a[j] = va1[k2][j]; }
      vf[0][k2] = u0.v;
      vf[1][k2] = u1.v;
    }

#pragma unroll
    for (int qt = 0; qt < 2; ++qt) {
      char* pq = pw + qt * 2304;
      f32x4 sc[4];
      __builtin_amdgcn_s_setprio(1);
#pragma unroll
      for (int kt = 0; kt < 4; ++kt) {
        f32x4 z = {};
        sc[kt] = __builtin_amdgcn_mfma_f32_16x16x32_bf16(kf[kt], qf[qt], z, 0, 0, 0);
      }
      __builtin_amdgcn_s_setprio(0);
      float pv[16], pm = -1e30f;
#pragma unroll
      for (int kt = 0; kt < 4; ++kt)
#pragma unroll
        for (int r = 0; r < 4; ++r) {
          float s = sc[kt][r] * SCL2;
          if (MASK) {
            if (kb + kt * 16 + lhi * 4 + r >= Se) s = -1e30f;
          }
          pv[kt * 4 + r] = s;
          pm = fmaxf(pm, s);
        }
      pm = fmaxf(pm, __shfl_xor(pm, 16));
      pm = fmaxf(pm, __shfl_xor(pm, 32));
      float mn = m_[qt];
      if (!__all(pm <= mn + 11.09f)) {
        mn = fmaxf(mn, pm);
        float csc = fexp2(m_[qt] - mn);
        m_[qt] = mn;
        l_[qt] *= csc;
#pragma unroll
        for (int dt = 0; dt < 2; ++dt)
#pragma unroll
          for (int r = 0; r < 4; ++r) ob[qt][dt][r] *= csc;
      }
      float rs = 0.0f;
#pragma unroll
      for (int i = 0; i < 16; ++i) {
        pv[i] = fexp2(pv[i] - mn);
        rs += pv[i];
      }
      rs += __shfl_xor(rs, 16);
      rs += __shfl_xor(rs, 32);
      l_[qt] += rs;
#pragma unroll
      for (int kt = 0; kt < 4; ++kt)
#pragma unroll
        for (int c = 0; c < 2; ++c)
          *(u32*)(pq + l16 * 144 + (kt * 16 + lhi * 4 + 2 * c) * 2) =
              cvtpk(pv[kt * 4 + 2 * c], pv[kt * 4 + 2 * c + 1]);
      __builtin_amdgcn_s_setprio(1);
#pragma unroll
      for (int k2 = 0; k2 < 2; ++k2) {
        bf16x8 pf = *(const bf16x8*)(pq + l16 * 144 + k2 * 64 + lhi * 16);
#pragma unroll
        for (int dt = 0; dt < 2; ++dt)
          ob[qt][dt] = __builtin_amdgcn_mfma_f32_16x16x32_bf16(vf[dt][k2], pf, ob[qt][dt], 0, 0, 0);
      }
      __builtin_amdgcn_s_setprio(0);
    }
  };

  int kb = 0;
  for (; kb + 64 <= Se; kb += 64) do_tile(kb, bconst<false>{});
  if (kb < Se) do_tile(kb, bconst<true>{});

#pragma unroll
  for (int qt = 0; qt < 2; ++qt) {
    float inv = 1.0f / l_[qt];
#pragma unroll
    for (int dt = 0; dt < 2; ++dt)
#pragma unroll
      for (int c = 0; c < 2; ++c)
        *(u32*)(pw + (qt * 16 + l16) * 80 + (dt * 16 + lhi * 4 + 2 * c) * 2) =
            cvtpk(ob[qt][dt][2 * c] * inv, ob[qt][dt][2 * c + 1] * inv);
  }
  asm volatile("s_waitcnt lgkmcnt(0)" ::: "memory");
  __builtin_amdgcn_sched_barrier(0);
  int qrow = qc * 32 + lane;
  if (lane < 32 && qrow < Se) {
#pragma unroll
    for (int c = 0; c < 4; ++c) {
      uint4 t = *(const uint4*)(pw + lane * 80 + c * 16);
      *(uint4*)((char*)ao + (size_t)(off + qrow) * 512 + h * 64 + c * 16) = t;
    }
  }
}

// ---------------- masked mean pooling: split-K partials ----------------------
__global__ void k_pool(const float* __restrict__ x, const int* __restrict__ offs,
                       float* __restrict__ pws) {
  int e = blockIdx.x, s = blockIdx.y, t = threadIdx.x;
  int off = offs[e], cnt = offs[e + 1] - off;
  int r0 = (cnt * s) >> 4, r1 = (cnt * (s + 1)) >> 4;
  float acc = 0.0f;
  for (int r = r0; r < r1; ++r) acc += x[(size_t)(off + r) * 256 + t];
  pws[((e << 4) + s) * 256 + t] = acc;
}

// ---------------- prediction head + L2 normalize -----------------------------
__global__ void k_head(const float* __restrict__ pws, const int* __restrict__ offs,
                       const float* __restrict__ w1, const float* __restrict__ b1,
                       const float* __restrict__ w2, const float* __restrict__ b2,
                       float* __restrict__ out) {
  __shared__ float le[256], hb[256], vec[3];
  int e = blockIdx.x, t = threadIdx.x;
  int cnt = offs[e + 1] - offs[e];
  float acc0 = 0.0f;
#pragma unroll
  for (int s = 0; s < 16; ++s) acc0 += pws[((e << 4) + s) * 256 + t];
  le[t] = acc0 / (float)max(cnt, 1);
  __syncthreads();
  float acc = b1[t];
  const float* wr = w1 + t * 256;
#pragma unroll 8
  for (int k = 0; k < 256; ++k) acc += le[k] * wr[k];
  hb[t] = fmaxf(acc, 0.0f);
  __syncthreads();
  if (t < 3) {
    float a = b2[t];
    const float* w = w2 + t * 256;
    for (int k = 0; k < 256; ++k) a += hb[k] * w[k];
    vec[t] = a;
  }
  __syncthreads();
  if (t < 3) {
    float n = sqrtf(vec[0] * vec[0] + vec[1] * vec[1] + vec[2] * vec[2]);
    out[e * 3 + t] = vec[t] / (n + 1e-8f);
  }
}

// ---------------- launch ------------------------------------------------------
extern "C" void kernel_launch(void* const* d_in, const int* in_sizes, int n_in,
                              void* d_out, int out_size, void* d_ws, size_t ws_size,
                              hipStream_t stream) {
  const float* dom_emb = (const float*)d_in[0];
  const float* geometry = (const float*)d_in[1];
  const float* geo_w1 = (const float*)d_in[2];
  const float* geo_b1 = (const float*)d_in[3];
  const float* geo_w2 = (const float*)d_in[4];
  const float* geo_b2 = (const float*)d_in[5];
  const float* qkv_w = (const float*)d_in[6];
  const float* qkv_b = (const float*)d_in[7];
  const float* out_w = (const float*)d_in[8];
  const float* out_b = (const float*)d_in[9];
  const float* ln1_w = (const float*)d_in[10];
  const float* ln1_b = (const float*)d_in[11];
  const float* ln2_w = (const float*)d_in[12];
  const float* ln2_b = (const float*)d_in[13];
  const float* ffn_w1 = (const float*)d_in[14];
  const float* ffn_b1 = (const float*)d_in[15];
  const float* ffn_w2 = (const float*)d_in[16];
  const float* ffn_b2 = (const float*)d_in[17];
  const float* head_w1 = (const float*)d_in[18];
  const float* head_b1 = (const float*)d_in[19];
  const float* head_w2 = (const float*)d_in[20];
  const float* head_b2 = (const float*)d_in[21];
  const int* dom_ids = (const int*)d_in[22];
  const int* d2e = (const int*)d_in[23];

  char* ws = (char*)d_ws;
  constexpr size_t OFF_OFFS = 0;
  constexpr size_t OFF_WBF = 512;
  constexpr size_t OFF_W2B = OFF_WBF + 3145728ull * 2;
  constexpr size_t OFF_H1 = OFF_W2B + 32768ull * 2;
  constexpr size_t OFF_GE = OFF_H1 + (size_t)MGEO_ * 128 * 2;
  constexpr size_t OFF_X = (OFF_GE + (size_t)MGEO_ * 256 * 4 + 255) & ~255ull;
  constexpr size_t OFF_H = OFF_X + (size_t)T_ * 256 * 4;
  constexpr size_t OFF_BIG = OFF_H + (size_t)T_ * 256 * 2;
  constexpr size_t OFF_PWS = OFF_BIG + (size_t)T_ * 1024 * 2;

  int* offs = (int*)(ws + OFF_OFFS);
  u16* wbf = (u16*)(ws + OFF_WBF);
  u16* wbf_qkv = wbf;
  u16* wbf_out = wbf + 786432;
  u16* wbf_f1 = wbf + 1048576;
  u16* wbf_f2 = wbf + 2097152;
  u16* w2b = (u16*)(ws + OFF_W2B);
  u16* h1 = (u16*)(ws + OFF_H1);
  float* ge = (float*)(ws + OFF_GE);
  float* x = (float*)(ws + OFF_X);
  u16* h = (u16*)(ws + OFF_H);
  u16* big = (u16*)(ws + OFF_BIG);
  float* pws = (float*)(ws + OFF_PWS);

  k_offsets<<<1, 128, 0, stream>>>(d2e, offs);
  k_f2b<<<256, 256, 0, stream>>>(qkv_w, wbf_qkv, L_ * 768 * 256);
  k_f2b<<<128, 256, 0, stream>>>(out_w, wbf_out, L_ * 256 * 256);
  k_f2b<<<256, 256, 0, stream>>>(ffn_w1, wbf_f1, L_ * 1024 * 256);
  k_f2b<<<256, 256, 0, stream>>>(ffn_w2, wbf_f2, L_ * 256 * 1024);
  k_f2b<<<32, 256, 0, stream>>>(geo_w2, w2b, 256 * 128);
  k_geo1<<<(NSENS_ * 128 + 255) / 256, 256, 0, stream>>>(geometry, geo_w1, geo_b1, h1);
  k_gemm<3><<<(MGEO_ / 128) * 2, 256, 0, stream>>>(h1, w2b, geo_b2, ge,
                                                   MGEO_, 256, 128, 2);
  k_featln<<<T_ / 4, 256, 0, stream>>>((const float4*)dom_emb, (const float4*)ge,
                                       dom_ids, ln1_w, ln1_b, (float4*)x, h);
  for (int l = 0; l < L_; ++l) {
    k_gemm<0><<<6 * 256, 256, 0, stream>>>(h, wbf_qkv + l * 196608, qkv_b + l * 768,
                                           big, T_, 768, 256, 6);
    k_attn<<<dim3(B_, 24), 512, 0, stream>>>(big, offs, h);
    k_gemm_ln<<<T_ / 64, 256, 0, stream>>>(h, wbf_out + l * 65536, out_b + l * 256,
                                           ln2_w + l * 256, ln2_b + l * 256, x, h, 256);
    k_gemm<1><<<8 * 256, 256, 0, stream>>>(h, wbf_f1 + l * 262144, ffn_b1 + l * 1024,
                                           big, T_, 1024, 256, 8);
    if (l < L_ - 1) {
      k_gemm_ln<<<T_ / 64, 256, 0, stream>>>(big, wbf_f2 + l * 262144, ffn_b2 + l * 256,
                                             ln1_w + (l + 1) * 256, ln1_b + (l + 1) * 256,
                                             x, h, 1024);
    } else {
      k_gemm<2><<<2 * 256, 256, 0, stream>>>(big, wbf_f2 + l * 262144, ffn_b2 + l * 256,
                                             x, T_, 256, 1024, 2);
    }
  }
  k_pool<<<dim3(B_, 16), 256, 0, stream>>>(x, offs, pws);
  k_head<<<B_, 256, 0, stream>>>(pws, offs, head_w1, head_b1, head_w2, head_b2, (float*)d_out);
}

// Round 13
// 898.900 us; speedup vs baseline: 1.3718x; 1.1388x over previous
//
#include <hip/hip_runtime.h>
#include <stdint.h>

typedef unsigned short u16;
typedef uint32_t u32;
typedef __bf16 bf16x8 __attribute__((ext_vector_type(8)));
typedef float f32x4 __attribute__((ext_vector_type(4)));

constexpr int T_ = 32768, D_ = 256, H_ = 8, L_ = 4, B_ = 64, NSENS_ = 5160;
constexpr int MGEO_ = 5248;  // NSENS_ padded to 41*128

template <bool Bv> struct bconst { static constexpr bool value = Bv; };

__device__ __forceinline__ u16 f2b(float f) {
  uint32_t u = __builtin_bit_cast(uint32_t, f);
  u += 0x7fffu + ((u >> 16) & 1u);
  return (u16)(u >> 16);
}
__device__ __forceinline__ float fexp2(float x) {
  float r;
  asm("v_exp_f32 %0, %1" : "=v"(r) : "v"(x));
  return r;
}
__device__ __forceinline__ u32 cvtpk(float lo, float hi) {
  u32 r;
  asm("v_cvt_pk_bf16_f32 %0, %1, %2" : "=v"(r) : "v"(lo), "v"(hi));
  return r;
}

__device__ __forceinline__ void gload16(const void* g, void* l) {
  __builtin_amdgcn_global_load_lds(
      (const __attribute__((address_space(1))) void*)g,
      (__attribute__((address_space(3))) void*)l, 16, 0, 0);
}

// ---------------- offsets via binary search (sorted dom_to_event_idx) --------
__global__ void k_offsets(const int* __restrict__ d2e, int* __restrict__ offs) {
  int t = threadIdx.x;
  if (t > B_) return;
  int lo = 0, hi = T_;
  while (lo < hi) { int mid = (lo + hi) >> 1; if (d2e[mid] < t) lo = mid + 1; else hi = mid; }
  offs[t] = lo;
}

// ---------------- f32 -> bf16 weight conversion (fused: 4 regions) ----------
__global__ void k_f2b4(const float* __restrict__ s0, const float* __restrict__ s1,
                       const float* __restrict__ s2, const float* __restrict__ s3,
                       u16* __restrict__ d) {
  // d: [0,786432) qkv | [786432,1048576) out | [1048576,2097152) f1 | [2097152,3145728) f2
  int i = blockIdx.x * blockDim.x + threadIdx.x;
  int str = gridDim.x * blockDim.x;
  for (; i < 3145728; i += str) {
    float v;
    if (i < 786432) v = s0[i];
    else if (i < 1048576) v = s1[i - 786432];
    else if (i < 2097152) v = s2[i - 1048576];
    else v = s3[i - 2097152];
    d[i] = f2b(v);
  }
}

__global__ void k_f2b(const float* __restrict__ s, u16* __restrict__ d, int n) {
  int i = blockIdx.x * blockDim.x + threadIdx.x;
  int str = gridDim.x * blockDim.x;
  for (; i < n; i += str) d[i] = f2b(s[i]);
}

// ---------------- geo MLP stage 1: h1 = gelu(geom/500 @ w1^T + b1), bf16 -----
__global__ void k_geo1(const float* __restrict__ geom, const float* __restrict__ w1,
                       const float* __restrict__ b1, u16* __restrict__ h1) {
  int i = blockIdx.x * blockDim.x + threadIdx.x;
  if (i >= NSENS_ * 128) return;
  int s = i >> 7, c = i & 127;
  float g0 = geom[s * 3 + 0] * (1.0f / 500.0f);
  float g1 = geom[s * 3 + 1] * (1.0f / 500.0f);
  float g2 = geom[s * 3 + 2] * (1.0f / 500.0f);
  float a = g0 * w1[c * 3 + 0] + g1 * w1[c * 3 + 1] + g2 * w1[c * 3 + 2] + b1[c];
  float g = 0.5f * a * (1.0f + erff(a * 0.70710678118654752f));
  h1[i] = f2b(g);
}

// ---------------- feat + layer-0 LN1: x = de + ge[dom]; h = LN(x) ------------
__global__ void k_featln(const float4* __restrict__ de, const float4* __restrict__ ge,
                         const int* __restrict__ dom_ids, const float* __restrict__ w,
                         const float* __restrict__ b, float4* __restrict__ x,
                         u16* __restrict__ h) {
  int row = blockIdx.x * 4 + (threadIdx.x >> 6);
  int lane = threadIdx.x & 63;
  int sid = dom_ids[row];
  float4 a = de[row * 64 + lane];
  float4 g = ge[sid * 64 + lane];
  float4 v;
  v.x = a.x + g.x; v.y = a.y + g.y; v.z = a.z + g.z; v.w = a.w + g.w;
  x[row * 64 + lane] = v;
  float s = v.x + v.y + v.z + v.w;
  float q = v.x * v.x + v.y * v.y + v.z * v.z + v.w * v.w;
#pragma unroll
  for (int m = 1; m < 64; m <<= 1) { s += __shfl_xor(s, m); q += __shfl_xor(q, m); }
  float mean = s * (1.0f / 256.0f);
  float var = fmaxf(q * (1.0f / 256.0f) - mean * mean, 0.0f);
  float rs = 1.0f / sqrtf(var + 1e-5f);
  float4 wv = *(const float4*)(w + lane * 4);
  float4 bv = *(const float4*)(b + lane * 4);
  ushort4 o;
  o.x = f2b((v.x - mean) * rs * wv.x + bv.x);
  o.y = f2b((v.y - mean) * rs * wv.y + bv.y);
  o.z = f2b((v.z - mean) * rs * wv.z + bv.z);
  o.w = f2b((v.w - mean) * rs * wv.w + bv.w);
  *(ushort4*)(h + (size_t)row * 256 + lane * 4) = o;
}

// ---------------- bf16 MFMA GEMM v2 (r10: double-buffered, PROVEN) -----------
// EPI: 0 = bf16 out, 1 = relu->bf16, 2 = f32 residual accumulate, 3 = f32 store
template <int EPI>
__global__ __launch_bounds__(256) void k_gemm(const u16* __restrict__ A, const u16* __restrict__ W,
                                              const float* __restrict__ bias, void* __restrict__ out,
                                              int M, int N, int K, int NXB) {
  __shared__ __align__(16) u16 lds[4 * 8192];
  const int nb = gridDim.x;
  const int id = blockIdx.x;
  const int gid = ((nb & 7) == 0) ? ((id & 7) * (nb >> 3) + (id >> 3)) : id;
  const int by = gid / NXB, bx = gid % NXB;
  const int m0 = by * 128, n0 = bx * 128;
  const int tid = threadIdx.x, lane = tid & 63, wv = tid >> 6;
  const int wr = wv >> 1, wc = wv & 1;
  const int l16 = lane & 15, lhi = lane >> 4;
  f32x4 acc[4][4] = {};
  const int NK = K >> 6;

  auto stage = [&](int buf, int kt) {
    char* lbase = (char*)lds + buf * 32768;
#pragma unroll
    for (int c = 0; c < 4; ++c) {
      int pb = c * 4096 + wv * 1024;
      int p = pb + lane * 16;
      int o = p ^ (((p >> 9) & 1) << 5);
      int row = o >> 7, colb = o & 127;
      gload16((const char*)A + ((size_t)(m0 + row) * K) * 2 + kt * 128 + colb, lbase + pb);
      gload16((const char*)W + ((size_t)(n0 + row) * K) * 2 + kt * 128 + colb,
              lbase + 16384 + pb);
    }
  };
  auto compute = [&](int buf) {
    const char* la = (const char*)lds + buf * 32768;
    const char* lb = la + 16384;
#pragma unroll
    for (int ks = 0; ks < 2; ++ks) {
      bf16x8 af[4], bfr[4];
#pragma unroll
      for (int i = 0; i < 4; ++i) {
        int ra = wr * 64 + i * 16 + l16;
        int oa = ra * 128 + ks * 64 + lhi * 16;
        af[i] = *(const bf16x8*)(la + (oa ^ (((oa >> 9) & 1) << 5)));
        int rb = wc * 64 + i * 16 + l16;
        int ob2 = rb * 128 + ks * 64 + lhi * 16;
        bfr[i] = *(const bf16x8*)(lb + (ob2 ^ (((ob2 >> 9) & 1) << 5)));
      }
#pragma unroll
      for (int i = 0; i < 4; ++i)
#pragma unroll
        for (int j = 0; j < 4; ++j)
          acc[i][j] = __builtin_amdgcn_mfma_f32_16x16x32_bf16(af[i], bfr[j], acc[i][j], 0, 0, 0);
    }
  };

  stage(0, 0);
  for (int kt = 0; kt < NK; ++kt) {
    int cur = kt & 1;
    if (kt + 1 < NK) {
      stage(cur ^ 1, kt + 1);
      asm volatile("s_waitcnt vmcnt(8)" ::: "memory");
    } else {
      asm volatile("s_waitcnt vmcnt(0)" ::: "memory");
    }
    __builtin_amdgcn_s_barrier();
    __builtin_amdgcn_sched_barrier(0);
    compute(cur);
    __builtin_amdgcn_sched_barrier(0);
    __builtin_amdgcn_s_barrier();
  }

  float bv[4];
#pragma unroll
  for (int j = 0; j < 4; ++j) bv[j] = bias[n0 + wc * 64 + j * 16 + l16];

  if (EPI <= 1) {
    char* ob_ = (char*)lds;
#pragma unroll
    for (int i = 0; i < 4; ++i)
#pragma unroll
      for (int j = 0; j < 4; ++j)
#pragma unroll
        for (int r = 0; r < 4; ++r) {
          int row = wr * 64 + i * 16 + lhi * 4 + r;
          int col = wc * 64 + j * 16 + l16;
          float v = acc[i][j][r] + bv[j];
          if (EPI == 1) v = fmaxf(v, 0.0f);
          int byte = row * 256 + col * 2;
          *(u16*)(ob_ + (byte ^ ((row & 3) << 5))) = f2b(v);
        }
    __syncthreads();
    int row2 = tid >> 1, half = tid & 1;
    char* dst = (char*)out + ((size_t)(m0 + row2) * N + n0) * 2 + half * 128;
#pragma unroll
    for (int c2 = 0; c2 < 8; ++c2) {
      int byte = row2 * 256 + half * 128 + c2 * 16;
      uint4 t = *(const uint4*)(ob_ + (byte ^ ((row2 & 3) << 5)));
      *(uint4*)(dst + c2 * 16) = t;
    }
  } else {
#pragma unroll
    for (int i = 0; i < 4; ++i)
#pragma unroll
      for (int j = 0; j < 4; ++j)
#pragma unroll
        for (int r = 0; r < 4; ++r) {
          int m = m0 + wr * 64 + i * 16 + lhi * 4 + r;
          int n = n0 + wc * 64 + j * 16 + l16;
          float val = acc[i][j][r] + bv[j];
          if (EPI == 2)
            ((float*)out)[(size_t)m * N + n] += val;
          else
            ((float*)out)[(size_t)m * N + n] = val;
        }
  }
}

// ---------------- fused GEMM + residual + LayerNorm (r10 dbuf, PROVEN) -------
__global__ __launch_bounds__(256) void k_gemm_ln(const u16* __restrict__ A,
                                                 const u16* __restrict__ W,
                                                 const float* __restrict__ bias,
                                                 const float* __restrict__ lnw,
                                                 const float* __restrict__ lnb,
                                                 float* __restrict__ x,
                                                 u16* __restrict__ hout, int K) {
  __shared__ __align__(16) u16 lds[2 * 20480];
  const int nb = gridDim.x;
  const int id = blockIdx.x;
  const int gid = (id & 7) * (nb >> 3) + (id >> 3);
  const int m0 = gid * 64;
  const int tid = threadIdx.x, lane = tid & 63, wv = tid >> 6;
  const int l16 = lane & 15, lhi = lane >> 4;
  f32x4 acc[4][4] = {};
  const int NK = K >> 6;

  auto stage = [&](int buf, int kt) {
    char* lbase = (char*)lds + buf * 40960;
#pragma unroll
    for (int c = 0; c < 10; ++c) {
      int pb = c * 4096 + wv * 1024;
      int p, reg;
      if (pb < 8192) { p = pb; reg = 0; } else { p = pb - 8192; reg = 1; }
      int pl = p + lane * 16;
      int o = pl ^ (((pl >> 9) & 1) << 5);
      int row = o >> 7, colb = o & 127;
      const char* src = reg == 0
          ? (const char*)A + ((size_t)(m0 + row) * K) * 2 + kt * 128 + colb
          : (const char*)W + ((size_t)row * K) * 2 + kt * 128 + colb;
      gload16(src, lbase + (reg ? 8192 : 0) + p);
    }
  };
  auto compute = [&](int buf) {
    const char* la = (const char*)lds + buf * 40960;
    const char* lb = la + 8192;
#pragma unroll
    for (int ks = 0; ks < 2; ++ks) {
      bf16x8 af[4], bfr[4];
#pragma unroll
      for (int i = 0; i < 4; ++i) {
        int oa = (i * 16 + l16) * 128 + ks * 64 + lhi * 16;
        af[i] = *(const bf16x8*)(la + (oa ^ (((oa >> 9) & 1) << 5)));
        int ob2 = (wv * 64 + i * 16 + l16) * 128 + ks * 64 + lhi * 16;
        bfr[i] = *(const bf16x8*)(lb + (ob2 ^ (((ob2 >> 9) & 1) << 5)));
      }
#pragma unroll
      for (int i = 0; i < 4; ++i)
#pragma unroll
        for (int j = 0; j < 4; ++j)
          acc[i][j] = __builtin_amdgcn_mfma_f32_16x16x32_bf16(af[i], bfr[j], acc[i][j], 0, 0, 0);
    }
  };

  stage(0, 0);
  for (int kt = 0; kt < NK; ++kt) {
    int cur = kt & 1;
    if (kt + 1 < NK) {
      stage(cur ^ 1, kt + 1);
      asm volatile("s_waitcnt vmcnt(10)" ::: "memory");
    } else {
      asm volatile("s_waitcnt vmcnt(0)" ::: "memory");
    }
    __builtin_amdgcn_s_barrier();
    __builtin_amdgcn_sched_barrier(0);
    compute(cur);
    __builtin_amdgcn_sched_barrier(0);
    __builtin_amdgcn_s_barrier();
  }

  float bv[4], wl[4], bl[4];
#pragma unroll
  for (int j = 0; j < 4; ++j) {
    int col = wv * 64 + j * 16 + l16;
    bv[j] = bias[col];
    wl[j] = lnw[col];
    bl[j] = lnb[col];
  }
#pragma unroll
  for (int i = 0; i < 4; ++i)
#pragma unroll
    for (int r = 0; r < 4; ++r) {
      int row = i * 16 + lhi * 4 + r;
#pragma unroll
      for (int j = 0; j < 4; ++j) {
        int col = wv * 64 + j * 16 + l16;
        acc[i][j][r] += bv[j] + x[(size_t)(m0 + row) * 256 + col];
      }
    }
  float* lr = (float*)lds;
  __syncthreads();
#pragma unroll
  for (int i = 0; i < 4; ++i)
#pragma unroll
    for (int r = 0; r < 4; ++r) {
      float s = 0.0f, q = 0.0f;
#pragma unroll
      for (int j = 0; j < 4; ++j) { float v = acc[i][j][r]; s += v; q += v * v; }
#pragma unroll
      for (int m = 1; m < 16; m <<= 1) { s += __shfl_xor(s, m); q += __shfl_xor(q, m); }
      if (l16 == 0) {
        int row = i * 16 + lhi * 4 + r;
        lr[wv * 64 + row] = s;
        lr[256 + wv * 64 + row] = q;
      }
    }
  __syncthreads();
  if (tid < 64) {
    float s = lr[tid] + lr[64 + tid] + lr[128 + tid] + lr[192 + tid];
    float q = lr[256 + tid] + lr[320 + tid] + lr[384 + tid] + lr[448 + tid];
    float mean = s * (1.0f / 256.0f);
    float var = fmaxf(q * (1.0f / 256.0f) - mean * mean, 0.0f);
    lr[512 + tid * 2] = mean;
    lr[512 + tid * 2 + 1] = 1.0f / sqrtf(var + 1e-5f);
  }
  __syncthreads();
#pragma unroll
  for (int i = 0; i < 4; ++i)
#pragma unroll
    for (int r = 0; r < 4; ++r) {
      int row = i * 16 + lhi * 4 + r;
      float mean = lr[512 + row * 2];
      float rstd = lr[512 + row * 2 + 1];
#pragma unroll
      for (int j = 0; j < 4; ++j) {
        int col = wv * 64 + j * 16 + l16;
        float v = acc[i][j][r];
        x[(size_t)(m0 + row) * 256 + col] = v;
        hout[(size_t)(m0 + row) * 256 + col] = f2b((v - mean) * rstd * wl[j] + bl[j]);
      }
    }
}

// ---------------- flash attention (r10 proven; LDS 4608B/wave) ----------------
// Block = (event, 32-q-chunk); 8 waves = 8 heads, independent (no barriers).
__global__ __launch_bounds__(512, 4) void k_attn(const u16* __restrict__ qkv,
                                                 const int* __restrict__ offs,
                                                 u16* __restrict__ ao) {
  const int e = blockIdx.x, qc = blockIdx.y;
  const int off = offs[e], Se = offs[e + 1] - off;
  if (qc * 32 >= Se) return;
  const int tid = threadIdx.x, lane = tid & 63, h = tid >> 6;
  const int l16 = lane & 15, lhi = lane >> 4;

  __shared__ __align__(16) char smem[8 * 4608];
  char* pw = smem + h * 4608;

  bf16x8 qf[2];
#pragma unroll
  for (int qt = 0; qt < 2; ++qt) {
    int qrow = qc * 32 + qt * 16 + l16;
    int g = off + min(qrow, Se - 1);
    qf[qt] = *(const bf16x8*)(qkv + (size_t)g * 768 + h * 32 + lhi * 8);
  }

  f32x4 ob[2][2] = {};
  float m_[2], l_[2];
#pragma unroll
  for (int qt = 0; qt < 2; ++qt) { m_[qt] = -1e30f; l_[qt] = 0.0f; }
  const float SCL2 = 0.25506974760143f;  // (1/sqrt(32)) * log2(e)

  auto do_tile = [&](int kb, auto mc) {
    constexpr bool MASK = decltype(mc)::value;
    bf16x8 kf[4];
#pragma unroll
    for (int kt = 0; kt < 4; ++kt) {
      int key = kb + kt * 16 + l16;
      if (MASK) key = min(key, Se - 1);
      kf[kt] = *(const bf16x8*)(qkv + (size_t)(off + key) * 768 + 256 + h * 32 + lhi * 8);
    }
    u16 va0[2][8], va1[2][8];
#pragma unroll
    for (int k2 = 0; k2 < 2; ++k2)
#pragma unroll
      for (int j = 0; j < 8; ++j) {
        int key = kb + k2 * 32 + lhi * 8 + j;
        if (MASK) key = min(key, Se - 1);
        const u16* p = qkv + (size_t)(off + key) * 768 + 512 + h * 32 + l16;
        va0[k2][j] = p[0];
        va1[k2][j] = p[16];
      }
    bf16x8 vf[2][2];
#pragma unroll
    for (int k2 = 0; k2 < 2; ++k2) {
      union { u16 a[8]; bf16x8 v; } u0, u1;
#pragma unroll
      for (int j = 0; j < 8; ++j) { u0.a[j] = va0[k2][j]; u1.a[j] = va1[k2][j]; }
      vf[0][k2] = u0.v;
      vf[1][k2] = u1.v;
    }

#pragma unroll
    for (int qt = 0; qt < 2; ++qt) {
      char* pq = pw + qt * 2304;
      f32x4 sc[4];
      __builtin_amdgcn_s_setprio(1);
#pragma unroll
      for (int kt = 0; kt < 4; ++kt) {
        f32x4 z = {};
        sc[kt] = __builtin_amdgcn_mfma_f32_16x16x32_bf16(kf[kt], qf[qt], z, 0, 0, 0);
      }
      __builtin_amdgcn_s_setprio(0);
      float pv[16], pm = -1e30f;
#pragma unroll
      for (int kt = 0; kt < 4; ++kt)
#pragma unroll
        for (int r = 0; r < 4; ++r) {
          float s = sc[kt][r] * SCL2;
          if (MASK) {
            if (kb + kt * 16 + lhi * 4 + r >= Se) s = -1e30f;
          }
          pv[kt * 4 + r] = s;
          pm = fmaxf(pm, s);
        }
      pm = fmaxf(pm, __shfl_xor(pm, 16));
      pm = fmaxf(pm, __shfl_xor(pm, 32));
      float mn = m_[qt];
      if (!__all(pm <= mn + 11.09f)) {
        mn = fmaxf(mn, pm);
        float csc = fexp2(m_[qt] - mn);
        m_[qt] = mn;
        l_[qt] *= csc;
#pragma unroll
        for (int dt = 0; dt < 2; ++dt)
#pragma unroll
          for (int r = 0; r < 4; ++r) ob[qt][dt][r] *= csc;
      }
      float rs = 0.0f;
#pragma unroll
      for (int i = 0; i < 16; ++i) {
        pv[i] = fexp2(pv[i] - mn);
        rs += pv[i];
      }
      rs += __shfl_xor(rs, 16);
      rs += __shfl_xor(rs, 32);
      l_[qt] += rs;
#pragma unroll
      for (int kt = 0; kt < 4; ++kt)
#pragma unroll
        for (int c = 0; c < 2; ++c)
          *(u32*)(pq + l16 * 144 + (kt * 16 + lhi * 4 + 2 * c) * 2) =
              cvtpk(pv[kt * 4 + 2 * c], pv[kt * 4 + 2 * c + 1]);
      __builtin_amdgcn_s_setprio(1);
#pragma unroll
      for (int k2 = 0; k2 < 2; ++k2) {
        bf16x8 pf = *(const bf16x8*)(pq + l16 * 144 + k2 * 64 + lhi * 16);
#pragma unroll
        for (int dt = 0; dt < 2; ++dt)
          ob[qt][dt] = __builtin_amdgcn_mfma_f32_16x16x32_bf16(vf[dt][k2], pf, ob[qt][dt], 0, 0, 0);
      }
      __builtin_amdgcn_s_setprio(0);
    }
  };

  int kb = 0;
  for (; kb + 64 <= Se; kb += 64) do_tile(kb, bconst<false>{});
  if (kb < Se) do_tile(kb, bconst<true>{});

#pragma unroll
  for (int qt = 0; qt < 2; ++qt) {
    float inv = 1.0f / l_[qt];
#pragma unroll
    for (int dt = 0; dt < 2; ++dt)
#pragma unroll
      for (int c = 0; c < 2; ++c)
        *(u32*)(pw + (qt * 16 + l16) * 80 + (dt * 16 + lhi * 4 + 2 * c) * 2) =
            cvtpk(ob[qt][dt][2 * c] * inv, ob[qt][dt][2 * c + 1] * inv);
  }
  asm volatile("s_waitcnt lgkmcnt(0)" ::: "memory");
  __builtin_amdgcn_sched_barrier(0);
  int qrow = qc * 32 + lane;
  if (lane < 32 && qrow < Se) {
#pragma unroll
    for (int c = 0; c < 4; ++c) {
      uint4 t = *(const uint4*)(pw + lane * 80 + c * 16);
      *(uint4*)((char*)ao + (size_t)(off + qrow) * 512 + h * 64 + c * 16) = t;
    }
  }
}

// ---------------- masked mean pooling: split-K partials ----------------------
__global__ void k_pool(const float* __restrict__ x, const int* __restrict__ offs,
                       float* __restrict__ pws) {
  int e = blockIdx.x, s = blockIdx.y, t = threadIdx.x;
  int off = offs[e], cnt = offs[e + 1] - off;
  int r0 = (cnt * s) >> 4, r1 = (cnt * (s + 1)) >> 4;
  float acc = 0.0f;
  for (int r = r0; r < r1; ++r) acc += x[(size_t)(off + r) * 256 + t];
  pws[((e << 4) + s) * 256 + t] = acc;
}

// ---------------- prediction head + L2 normalize -----------------------------
__global__ void k_head(const float* __restrict__ pws, const int* __restrict__ offs,
                       const float* __restrict__ w1, const float* __restrict__ b1,
                       const float* __restrict__ w2, const float* __restrict__ b2,
                       float* __restrict__ out) {
  __shared__ float le[256], hb[256], vec[3];
  int e = blockIdx.x, t = threadIdx.x;
  int cnt = offs[e + 1] - offs[e];
  float acc0 = 0.0f;
#pragma unroll
  for (int s = 0; s < 16; ++s) acc0 += pws[((e << 4) + s) * 256 + t];
  le[t] = acc0 / (float)max(cnt, 1);
  __syncthreads();
  float acc = b1[t];
  const float* wr = w1 + t * 256;
#pragma unroll 8
  for (int k = 0; k < 256; ++k) acc += le[k] * wr[k];
  hb[t] = fmaxf(acc, 0.0f);
  __syncthreads();
  if (t < 3) {
    float a = b2[t];
    const float* w = w2 + t * 256;
    for (int k = 0; k < 256; ++k) a += hb[k] * w[k];
    vec[t] = a;
  }
  __syncthreads();
  if (t < 3) {
    float n = sqrtf(vec[0] * vec[0] + vec[1] * vec[1] + vec[2] * vec[2]);
    out[e * 3 + t] = vec[t] / (n + 1e-8f);
  }
}

// ---------------- launch ------------------------------------------------------
extern "C" void kernel_launch(void* const* d_in, const int* in_sizes, int n_in,
                              void* d_out, int out_size, void* d_ws, size_t ws_size,
                              hipStream_t stream) {
  const float* dom_emb = (const float*)d_in[0];
  const float* geometry = (const float*)d_in[1];
  const float* geo_w1 = (const float*)d_in[2];
  const float* geo_b1 = (const float*)d_in[3];
  const float* geo_w2 = (const float*)d_in[4];
  const float* geo_b2 = (const float*)d_in[5];
  const float* qkv_w = (const float*)d_in[6];
  const float* qkv_b = (const float*)d_in[7];
  const float* out_w = (const float*)d_in[8];
  const float* out_b = (const float*)d_in[9];
  const float* ln1_w = (const float*)d_in[10];
  const float* ln1_b = (const float*)d_in[11];
  const float* ln2_w = (const float*)d_in[12];
  const float* ln2_b = (const float*)d_in[13];
  const float* ffn_w1 = (const float*)d_in[14];
  const float* ffn_b1 = (const float*)d_in[15];
  const float* ffn_w2 = (const float*)d_in[16];
  const float* ffn_b2 = (const float*)d_in[17];
  const float* head_w1 = (const float*)d_in[18];
  const float* head_b1 = (const float*)d_in[19];
  const float* head_w2 = (const float*)d_in[20];
  const float* head_b2 = (const float*)d_in[21];
  const int* dom_ids = (const int*)d_in[22];
  const int* d2e = (const int*)d_in[23];

  char* ws = (char*)d_ws;
  constexpr size_t OFF_OFFS = 0;
  constexpr size_t OFF_WBF = 512;
  constexpr size_t OFF_W2B = OFF_WBF + 3145728ull * 2;
  constexpr size_t OFF_H1 = OFF_W2B + 32768ull * 2;
  constexpr size_t OFF_GE = OFF_H1 + (size_t)MGEO_ * 128 * 2;
  constexpr size_t OFF_X = (OFF_GE + (size_t)MGEO_ * 256 * 4 + 255) & ~255ull;
  constexpr size_t OFF_H = OFF_X + (size_t)T_ * 256 * 4;
  constexpr size_t OFF_BIG = OFF_H + (size_t)T_ * 256 * 2;
  constexpr size_t OFF_PWS = OFF_BIG + (size_t)T_ * 1024 * 2;

  int* offs = (int*)(ws + OFF_OFFS);
  u16* wbf = (u16*)(ws + OFF_WBF);
  u16* wbf_qkv = wbf;
  u16* wbf_out = wbf + 786432;
  u16* wbf_f1 = wbf + 1048576;
  u16* wbf_f2 = wbf + 2097152;
  u16* w2b = (u16*)(ws + OFF_W2B);
  u16* h1 = (u16*)(ws + OFF_H1);
  float* ge = (float*)(ws + OFF_GE);
  float* x = (float*)(ws + OFF_X);
  u16* h = (u16*)(ws + OFF_H);
  u16* big = (u16*)(ws + OFF_BIG);
  float* pws = (float*)(ws + OFF_PWS);

  k_offsets<<<1, 128, 0, stream>>>(d2e, offs);
  k_f2b4<<<512, 256, 0, stream>>>(qkv_w, out_w, ffn_w1, ffn_w2, wbf);
  k_f2b<<<32, 256, 0, stream>>>(geo_w2, w2b, 256 * 128);
  k_geo1<<<(NSENS_ * 128 + 255) / 256, 256, 0, stream>>>(geometry, geo_w1, geo_b1, h1);
  k_gemm<3><<<(MGEO_ / 128) * 2, 256, 0, stream>>>(h1, w2b, geo_b2, ge,
                                                   MGEO_, 256, 128, 2);
  k_featln<<<T_ / 4, 256, 0, stream>>>((const float4*)dom_emb, (const float4*)ge,
                                       dom_ids, ln1_w, ln1_b, (float4*)x, h);
  for (int l = 0; l < L_; ++l) {
    k_gemm<0><<<6 * 256, 256, 0, stream>>>(h, wbf_qkv + l * 196608, qkv_b + l * 768,
                                           big, T_, 768, 256, 6);
    k_attn<<<dim3(B_, 24), 512, 0, stream>>>(big, offs, h);
    k_gemm_ln<<<T_ / 64, 256, 0, stream>>>(h, wbf_out + l * 65536, out_b + l * 256,
                                           ln2_w + l * 256, ln2_b + l * 256, x, h, 256);
    k_gemm<1><<<8 * 256, 256, 0, stream>>>(h, wbf_f1 + l * 262144, ffn_b1 + l * 1024,
                                           big, T_, 1024, 256, 8);
    if (l < L_ - 1) {
      k_gemm_ln<<<T_ / 64, 256, 0, stream>>>(big, wbf_f2 + l * 262144, ffn_b2 + l * 256,
                                             ln1_w + (l + 1) * 256, ln1_b + (l + 1) * 256,
                                             x, h, 1024);
    } else {
      k_gemm<2><<<2 * 256, 256, 0, stream>>>(big, wbf_f2 + l * 262144, ffn_b2 + l * 256,
                                             x, T_, 256, 1024, 2);
    }
  }
  k_pool<<<dim3(B_, 16), 256, 0, stream>>>(x, offs, pws);
  k_head<<<B_, 256, 0, stream>>>(pws, offs, head_w1, head_b1, head_w2, head_b2, (float*)d_out);
}